// Round 5
// baseline (339.658 us; speedup 1.0000x reference)
//
#include <hip/hip_runtime.h>
#include <hip/hip_bf16.h>

typedef __bf16 bf16;
typedef bf16 bf16x8 __attribute__((ext_vector_type(8)));
typedef bf16 bf16x4 __attribute__((ext_vector_type(4)));
typedef float f32x4 __attribute__((ext_vector_type(4)));

#define AS1 __attribute__((address_space(1)))
#define AS3 __attribute__((address_space(3)))

__device__ __forceinline__ void gload_lds16(const void* g, void* l) {
    __builtin_amdgcn_global_load_lds((const AS1 void*)g, (AS3 void*)l, 16, 0, 0);
}

__device__ __forceinline__ float tanh_fast(float x) {
    float xx = fminf(fmaxf(x, -15.0f), 15.0f);
    float e = __expf(2.0f * xx);
    return (e - 1.0f) / (e + 1.0f);
}

// ---------------------------------------------------------------------------
// Kernel 1: convert e1,e2 -> bf16 X=[e1|e2] (row-major [8192][4096]) and
// compute zs[m][c] = (1/2048) * dot(e1[r]*e2[r], W[c])  with r = 2048*m + c.
// ---------------------------------------------------------------------------
__global__ __launch_bounds__(256) void conv_x_zs(
    const float* __restrict__ e1, const float* __restrict__ e2,
    const float* __restrict__ W, bf16* __restrict__ Xb, float* __restrict__ zs)
{
    const int r = blockIdx.x;           // 0..8191
    const int t = threadIdx.x;          // 0..255, 8 elems each
    const int c = r & 2047, m = r >> 11;
    const size_t rb = (size_t)r * 2048;

    const float4* p1 = (const float4*)(e1 + rb) + t * 2;
    const float4* p2 = (const float4*)(e2 + rb) + t * 2;
    const float4* pw = (const float4*)(W + (size_t)c * 2048) + t * 2;
    float4 a0 = p1[0], a1 = p1[1];
    float4 b0 = p2[0], b1 = p2[1];
    float4 w0 = pw[0], w1 = pw[1];

    float dot = a0.x*b0.x*w0.x + a0.y*b0.y*w0.y + a0.z*b0.z*w0.z + a0.w*b0.w*w0.w
              + a1.x*b1.x*w1.x + a1.y*b1.y*w1.y + a1.z*b1.z*w1.z + a1.w*b1.w*w1.w;

    bf16x8 xa, xb;
    xa[0]=(bf16)a0.x; xa[1]=(bf16)a0.y; xa[2]=(bf16)a0.z; xa[3]=(bf16)a0.w;
    xa[4]=(bf16)a1.x; xa[5]=(bf16)a1.y; xa[6]=(bf16)a1.z; xa[7]=(bf16)a1.w;
    xb[0]=(bf16)b0.x; xb[1]=(bf16)b0.y; xb[2]=(bf16)b0.z; xb[3]=(bf16)b0.w;
    xb[4]=(bf16)b1.x; xb[5]=(bf16)b1.y; xb[6]=(bf16)b1.z; xb[7]=(bf16)b1.w;

    *(bf16x8*)(Xb + (size_t)r * 4096 + t * 8)        = xa;
    *(bf16x8*)(Xb + (size_t)r * 4096 + 2048 + t * 8) = xb;

    #pragma unroll
    for (int off = 32; off; off >>= 1) dot += __shfl_xor(dot, off);
    __shared__ float red[4];
    if ((t & 63) == 0) red[t >> 6] = dot;
    __syncthreads();
    if (t == 0) zs[m * 2048 + c] = (red[0] + red[1] + red[2] + red[3]) * (1.0f / 2048.0f);
}

// ---------------------------------------------------------------------------
// Kernel 2: V [4096][2048] f32  ->  Vt [2048][4096] bf16 (transposed, B^T)
// ---------------------------------------------------------------------------
__global__ __launch_bounds__(256) void conv_vt(const float* __restrict__ V,
                                               bf16* __restrict__ Vt)
{
    __shared__ float tile[64][65];
    const int k0 = (blockIdx.x >> 5) * 64;  // 64 k-tiles
    const int c0 = (blockIdx.x & 31) * 64;  // 32 c-tiles
    const int t = threadIdx.x;
    const int rr = t >> 4;
    const int cc = (t & 15) * 4;

    #pragma unroll
    for (int r4 = 0; r4 < 4; ++r4) {
        int row = r4 * 16 + rr;
        float4 v = *(const float4*)(V + (size_t)(k0 + row) * 2048 + c0 + cc);
        tile[row][cc + 0] = v.x; tile[row][cc + 1] = v.y;
        tile[row][cc + 2] = v.z; tile[row][cc + 3] = v.w;
    }
    __syncthreads();
    #pragma unroll
    for (int r4 = 0; r4 < 4; ++r4) {
        int crow = r4 * 16 + rr;   // c index within tile
        bf16x4 o;
        o[0] = (bf16)tile[cc + 0][crow];
        o[1] = (bf16)tile[cc + 1][crow];
        o[2] = (bf16)tile[cc + 2][crow];
        o[3] = (bf16)tile[cc + 3][crow];
        *(bf16x4*)(Vt + (size_t)(c0 + crow) * 4096 + k0 + cc) = o;
    }
}

// ---------------------------------------------------------------------------
// Kernel 3: 256x256-tile GEMM, software-pipelined one-phase-ahead reads.
// Per K-step t (buf c=t&1, o=c^1), entry invariant: aA=A0(c), bB0=B0(c),
// bB1=B1(c) in regs; tile t+1 landed & visible.
//   P1: rd A1(c)->aN (8)      | q00 = aA x bB0
//   P2:                       | q01 = aA x bB1
//   lgkmcnt(0); BARRIER1            (all reads of buf c drained, all waves)
//   stage tile t+2 -> buf c (8 gloads); vmcnt(8); BARRIER2
//                                    (tile t+1 landed per-wave + visible)
//   P3: rd A0(o)->aA (8)      | q11 = aN x bB1
//   P4: rd B1(o)->bB1 (4)     | q10 = aN x bB0
//   P5: rd B0(o)->bB0 (4)       (drains under next step's q00 wait)
// Reads for each MFMA cluster issue >=1 cluster earlier -> LDS drain hides
// under MFMA (m196's fine interleave). Counted vmcnt(8) never drains to 0
// in steady state. T2 swizzle as before (conflicts measured 0).
// ---------------------------------------------------------------------------
__global__ __launch_bounds__(512, 2) void gemm_ep(
    const bf16* __restrict__ Xb, const bf16* __restrict__ Vt,
    const float* __restrict__ zs, const float* __restrict__ bias,
    float* __restrict__ out)
{
    extern __shared__ char smem[];     // 131072 bytes
    const int tid  = threadIdx.x;
    const int lane = tid & 63;
    const int wid  = tid >> 6;
    const int wr = wid >> 2, wc = wid & 3;
    const int mtile = blockIdx.x >> 3;   // 32 row tiles
    const int ntile = blockIdx.x & 7;    // 8 col tiles (ntile == XCD id)
    const int row0 = mtile * 256, col0 = ntile * 256;

    const int srow = tid >> 3;                               // 0..63
    const int scb  = ((tid & 7) * 16) ^ ((srow & 7) << 4);   // swizzled byte col
    const bf16* Abase = Xb + (size_t)(row0 + srow) * 4096 + (scb >> 1);
    const bf16* Bbase = Vt + (size_t)(col0 + srow) * 4096 + (scb >> 1);

    const int lr  = lane & 15;
    const int lkb = (lane >> 4) * 16;

    f32x4 acc[2][2][4][2] = {};   // [qm][qn][i][j]
    bf16x8 aA[4][2], aN[4][2];    // A half cur (q00/q01) / next (q11/q10)
    bf16x8 bB0[2][2], bB1[2][2];  // B halves, resident whole K-step

    auto stage = [&](int c, const bf16* Ag, const bf16* Bg) {
        char* Al = smem + c * 65536 + tid * 16;
        char* Bl = smem + c * 65536 + 32768 + tid * 16;
        #pragma unroll
        for (int r = 0; r < 4; ++r) gload_lds16(Ag + (size_t)r * 262144, Al + r * 8192);
        #pragma unroll
        for (int r = 0; r < 4; ++r) gload_lds16(Bg + (size_t)r * 262144, Bl + r * 8192);
    };
    auto rdA = [&](bf16x8 (&dst)[4][2], const char* Ab, int half) {
        #pragma unroll
        for (int i = 0; i < 4; ++i)
            #pragma unroll
            for (int ks = 0; ks < 2; ++ks) {
                const int R = wr * 128 + half * 64 + i * 16 + lr;
                const int cb = ks * 64 + lkb;
                dst[i][ks] = *(const bf16x8*)(Ab + R * 128 + (cb ^ ((R & 7) << 4)));
            }
    };
    auto rdB = [&](bf16x8 (&dst)[2][2], const char* Bb, int half) {
        #pragma unroll
        for (int j = 0; j < 2; ++j)
            #pragma unroll
            for (int ks = 0; ks < 2; ++ks) {
                const int R = wc * 64 + half * 32 + j * 16 + lr;
                const int cb = ks * 64 + lkb;
                dst[j][ks] = *(const bf16x8*)(Bb + R * 128 + (cb ^ ((R & 7) << 4)));
            }
    };
    auto quad = [&](f32x4 (&a)[4][2], bf16x8 (&av)[4][2], bf16x8 (&bv)[2][2]) {
        __builtin_amdgcn_s_setprio(1);
        #pragma unroll
        for (int ks = 0; ks < 2; ++ks)
            #pragma unroll
            for (int i = 0; i < 4; ++i)
                #pragma unroll
                for (int j = 0; j < 2; ++j)
                    a[i][j] = __builtin_amdgcn_mfma_f32_16x16x32_bf16(
                        av[i][ks], bv[j][ks], a[i][j], 0, 0, 0);
        __builtin_amdgcn_s_setprio(0);
    };

    // prologue: tiles 0,1 staged; drain both (cheap once); initial reg loads
    stage(0, Abase, Bbase);
    stage(1, Abase + 64, Bbase + 64);
    asm volatile("s_waitcnt vmcnt(0)" ::: "memory");
    __builtin_amdgcn_s_barrier();
    rdA(aA,  smem,         0);
    rdB(bB0, smem + 32768, 0);
    rdB(bB1, smem + 32768, 1);

    const bf16* AgS = Abase + 128;   // staging ptr, tile kt=2 onward
    const bf16* BgS = Bbase + 128;

    #pragma unroll 2
    for (int t = 0; t < 62; ++t) {
        const int c = t & 1, o = c ^ 1;
        const char* Ac = smem + c * 65536;
        const char* Ao = smem + o * 65536;

        rdA(aN, Ac, 1);                       // P1 reads (for q11/q10)
        quad(acc[0][0], aA, bB0);             // q00
        quad(acc[0][1], aA, bB1);             // q01
        asm volatile("s_waitcnt lgkmcnt(0)" ::: "memory");
        __builtin_amdgcn_s_barrier();         // buf c reads done (all waves)
        stage(c, AgS, BgS);                   // tile t+2 -> buf c
        AgS += 64; BgS += 64;
        asm volatile("s_waitcnt vmcnt(8)" ::: "memory");  // tile t+1 landed
        __builtin_amdgcn_s_barrier();         // ...and visible to all waves
        rdA(aA, Ao, 0);                       // P3 reads (tile t+1, next q00/q01)
        quad(acc[1][1], aN, bB1);             // q11
        rdB(bB1, Ao + 32768, 1);              // P4 reads (next q01)
        quad(acc[1][0], aN, bB0);             // q10
        rdB(bB0, Ao + 32768, 0);              // P5 reads (next q00)
    }

    // t = 62 (c=0, o=1): no stage; full vmcnt drain for tile 63
    {
        const char* Ac = smem;
        const char* Ao = smem + 65536;
        rdA(aN, Ac, 1);
        quad(acc[0][0], aA, bB0);
        quad(acc[0][1], aA, bB1);
        asm volatile("s_waitcnt lgkmcnt(0)" ::: "memory");
        __builtin_amdgcn_s_barrier();
        asm volatile("s_waitcnt vmcnt(0)" ::: "memory");  // tile 63 landed
        __builtin_amdgcn_s_barrier();
        rdA(aA, Ao, 0);
        quad(acc[1][1], aN, bB1);
        rdB(bB1, Ao + 32768, 1);
        quad(acc[1][0], aN, bB0);
        rdB(bB0, Ao + 32768, 0);
    }
    // t = 63 (buf 1): final K-step, no staging/barriers
    {
        const char* Ac = smem + 65536;
        rdA(aN, Ac, 1);
        quad(acc[0][0], aA, bB0);
        quad(acc[0][1], aA, bB1);
        quad(acc[1][1], aN, bB1);
        quad(acc[1][0], aN, bB0);
    }

    // epilogue: out = tanh(acc + zs[p%4][c] + bias[c])
    // C/D layout (m89): col = lane&15, row = (lane>>4)*4 + q; p%4 == q here.
    const int lq = lane >> 4;
    #pragma unroll
    for (int qn = 0; qn < 2; ++qn)
        #pragma unroll
        for (int j = 0; j < 2; ++j) {
            const int ccol = col0 + wc * 64 + qn * 32 + j * 16 + lr;
            const float bb = bias[ccol];
            float zrow[4];
            #pragma unroll
            for (int q = 0; q < 4; ++q) zrow[q] = zs[q * 2048 + ccol] + bb;
            #pragma unroll
            for (int qm = 0; qm < 2; ++qm)
                #pragma unroll
                for (int i = 0; i < 4; ++i) {
                    const int prow = row0 + wr * 128 + qm * 64 + i * 16 + lq * 4;
                    #pragma unroll
                    for (int q = 0; q < 4; ++q)
                        out[(size_t)(prow + q) * 2048 + ccol] =
                            tanh_fast(acc[qm][qn][i][j][q] + zrow[q]);
                }
        }
}

// ---------------------------------------------------------------------------
extern "C" void kernel_launch(void* const* d_in, const int* in_sizes, int n_in,
                              void* d_out, int out_size, void* d_ws, size_t ws_size,
                              hipStream_t stream) {
    const float* e1 = (const float*)d_in[0];   // (8192, 2048)
    const float* e2 = (const float*)d_in[1];   // (8192, 2048)
    const float* W  = (const float*)d_in[2];   // (2048, 2048)
    const float* V  = (const float*)d_in[3];   // (4096, 2048)
    const float* b  = (const float*)d_in[4];   // (2048,)
    float* out = (float*)d_out;                // (8192, 2048) f32

    char* ws = (char*)d_ws;
    bf16*  Xb = (bf16*)ws;                                  // 64 MiB
    bf16*  Vt = (bf16*)(ws + (size_t)64 * 1024 * 1024);     // 16 MiB
    float* zs = (float*)(ws + (size_t)80 * 1024 * 1024);    // 32 KiB

    conv_x_zs<<<8192, 256, 0, stream>>>(e1, e2, W, Xb, zs);
    conv_vt<<<2048, 256, 0, stream>>>(V, Vt);

    hipFuncSetAttribute((const void*)gemm_ep,
                        hipFuncAttributeMaxDynamicSharedMemorySize, 131072);
    gemm_ep<<<256, 512, 131072, stream>>>(Xb, Vt, zs, b, out);
}

// Round 7
// 205.936 us; speedup vs baseline: 1.6493x; 1.6493x over previous
//
#include <hip/hip_runtime.h>
#include <hip/hip_bf16.h>

typedef __bf16 bf16;
typedef bf16 bf16x8 __attribute__((ext_vector_type(8)));
typedef bf16 bf16x4 __attribute__((ext_vector_type(4)));
typedef float f32x4 __attribute__((ext_vector_type(4)));

#define AS1 __attribute__((address_space(1)))
#define AS3 __attribute__((address_space(3)))

__device__ __forceinline__ void gload_lds16(const void* g, void* l) {
    __builtin_amdgcn_global_load_lds((const AS1 void*)g, (AS3 void*)l, 16, 0, 0);
}

__device__ __forceinline__ float tanh_fast(float x) {
    float xx = fminf(fmaxf(x, -15.0f), 15.0f);
    float e = __expf(2.0f * xx);
    return (e - 1.0f) / (e + 1.0f);
}

// ---------------------------------------------------------------------------
// Kernel 1: convert e1,e2 -> bf16 X=[e1|e2] (row-major [8192][4096]) and
// compute zs[m][c] = (1/2048) * dot(e1[r]*e2[r], W[c])  with r = 2048*m + c.
// ---------------------------------------------------------------------------
__global__ __launch_bounds__(256) void conv_x_zs(
    const float* __restrict__ e1, const float* __restrict__ e2,
    const float* __restrict__ W, bf16* __restrict__ Xb, float* __restrict__ zs)
{
    const int r = blockIdx.x;           // 0..8191
    const int t = threadIdx.x;          // 0..255, 8 elems each
    const int c = r & 2047, m = r >> 11;
    const size_t rb = (size_t)r * 2048;

    const float4* p1 = (const float4*)(e1 + rb) + t * 2;
    const float4* p2 = (const float4*)(e2 + rb) + t * 2;
    const float4* pw = (const float4*)(W + (size_t)c * 2048) + t * 2;
    float4 a0 = p1[0], a1 = p1[1];
    float4 b0 = p2[0], b1 = p2[1];
    float4 w0 = pw[0], w1 = pw[1];

    float dot = a0.x*b0.x*w0.x + a0.y*b0.y*w0.y + a0.z*b0.z*w0.z + a0.w*b0.w*w0.w
              + a1.x*b1.x*w1.x + a1.y*b1.y*w1.y + a1.z*b1.z*w1.z + a1.w*b1.w*w1.w;

    bf16x8 xa, xb;
    xa[0]=(bf16)a0.x; xa[1]=(bf16)a0.y; xa[2]=(bf16)a0.z; xa[3]=(bf16)a0.w;
    xa[4]=(bf16)a1.x; xa[5]=(bf16)a1.y; xa[6]=(bf16)a1.z; xa[7]=(bf16)a1.w;
    xb[0]=(bf16)b0.x; xb[1]=(bf16)b0.y; xb[2]=(bf16)b0.z; xb[3]=(bf16)b0.w;
    xb[4]=(bf16)b1.x; xb[5]=(bf16)b1.y; xb[6]=(bf16)b1.z; xb[7]=(bf16)b1.w;

    *(bf16x8*)(Xb + (size_t)r * 4096 + t * 8)        = xa;
    *(bf16x8*)(Xb + (size_t)r * 4096 + 2048 + t * 8) = xb;

    #pragma unroll
    for (int off = 32; off; off >>= 1) dot += __shfl_xor(dot, off);
    __shared__ float red[4];
    if ((t & 63) == 0) red[t >> 6] = dot;
    __syncthreads();
    if (t == 0) zs[m * 2048 + c] = (red[0] + red[1] + red[2] + red[3]) * (1.0f / 2048.0f);
}

// ---------------------------------------------------------------------------
// Kernel 2: V [4096][2048] f32  ->  Vt [2048][4096] bf16 (transposed, B^T)
// ---------------------------------------------------------------------------
__global__ __launch_bounds__(256) void conv_vt(const float* __restrict__ V,
                                               bf16* __restrict__ Vt)
{
    __shared__ float tile[64][65];
    const int k0 = (blockIdx.x >> 5) * 64;  // 64 k-tiles
    const int c0 = (blockIdx.x & 31) * 64;  // 32 c-tiles
    const int t = threadIdx.x;
    const int rr = t >> 4;
    const int cc = (t & 15) * 4;

    #pragma unroll
    for (int r4 = 0; r4 < 4; ++r4) {
        int row = r4 * 16 + rr;
        float4 v = *(const float4*)(V + (size_t)(k0 + row) * 2048 + c0 + cc);
        tile[row][cc + 0] = v.x; tile[row][cc + 1] = v.y;
        tile[row][cc + 2] = v.z; tile[row][cc + 3] = v.w;
    }
    __syncthreads();
    #pragma unroll
    for (int r4 = 0; r4 < 4; ++r4) {
        int crow = r4 * 16 + rr;   // c index within tile
        bf16x4 o;
        o[0] = (bf16)tile[cc + 0][crow];
        o[1] = (bf16)tile[cc + 1][crow];
        o[2] = (bf16)tile[cc + 2][crow];
        o[3] = (bf16)tile[cc + 3][crow];
        *(bf16x4*)(Vt + (size_t)(c0 + crow) * 4096 + k0 + cc) = o;
    }
}

// ---------------------------------------------------------------------------
// Kernel 3: 256x256 8-phase GEMM. Staged half-tiles == per-phase read sets:
//   A region H (16KB): global rows H*64 + {0,128} + [0,64)   (read at P1/P3)
//   B region H (16KB): global rows H*32 + {0,64,128,192} + [0,32)  (P1/P2)
// (global_load_lds source addr is per-lane, so strips are fine; LDS dst is
// linear; T2 swizzle via inverse-swizzled source col, key = (ldsrow&7)<<4.)
// Per K-tile t (buf c=t&1, o=c^1), 4 phases x {reads | 1 half-tile stage |
// BAR | lgkm0 | MFMA quadrant | BAR}:
//   P1: rdA(c,0)+rdB0(c,0) | stage B1(t+1)->o | q00     [B1(o) dead @(t-1).P2]
//   P2: rdB1(c,1)          | stage A0(t+2)->c | q01     [A0(c) dead @P1]
//   P3: rdA(c,1)           | stage B0(t+2)->c | q11     [B0(c) dead @P1]
//   P4:                    | stage A1(t+2)->c | vmcnt(6) | q10 [A1(c) dead @P3]
// "dead": last ds_read in phase k-1 => all waves lgkm-drained it before
// passing bar_(k-1)2, so a stage issued in phase k can never land early.
// vmcnt(6) once per K-tile leaves exactly {A0,B0,A1}(t+2) in flight (3 half-
// tiles, m201 invariant) and guarantees all of tile t+1 landed before t+1.P1.
// Fragment<->lane mapping identical to verified r4; only LDS placement moved.
// ---------------------------------------------------------------------------
__global__ __launch_bounds__(512, 2) void gemm_ep(
    const bf16* __restrict__ Xb, const bf16* __restrict__ Vt,
    const float* __restrict__ zs, const float* __restrict__ bias,
    float* __restrict__ out)
{
    extern __shared__ char smem[];     // 131072 bytes
    const int tid  = threadIdx.x;
    const int lane = tid & 63;
    const int wid  = tid >> 6;
    const int wr = wid >> 2, wc = wid & 3;
    const int mtile = blockIdx.x >> 3;   // 32 row tiles
    const int ntile = blockIdx.x & 7;    // 8 col tiles (ntile == XCD id)
    const int row0 = mtile * 256, col0 = ntile * 256;

    const int srow = tid >> 3;                               // 0..63
    const int scb  = ((tid & 7) * 16) ^ ((srow & 7) << 4);   // swizzled byte col
    const bf16* Abase = Xb + (size_t)(row0 + srow) * 4096 + (scb >> 1);
    const bf16* Bbase = Vt + (size_t)(col0 + (srow & 31) + ((srow >> 5) << 6)) * 4096
                           + (scb >> 1);

    const int lr   = lane & 15;
    const int lkb  = (lane >> 4) * 16;
    const int keyx = (lr & 7) << 4;      // read-side swizzle key (== ldsrow&7)

    f32x4 acc[2][2][4][2] = {};   // [qm][qn][i][j]
    bf16x8 aA[4][2];              // A fragment of current phase-half
    bf16x8 bB0[2][2], bB1[2][2];  // B fragments, resident whole K-tile

    auto stageA = [&](int c, int H, int kt) {
        char* dst = smem + c * 65536 + H * 16384 + tid * 16;
        const bf16* src = Abase + (size_t)(H * 64) * 4096 + kt * 64;
        gload_lds16(src, dst);
        gload_lds16(src + (size_t)128 * 4096, dst + 8192);
    };
    auto stageB = [&](int c, int H, int kt) {
        char* dst = smem + c * 65536 + 32768 + H * 16384 + tid * 16;
        const bf16* src = Bbase + (size_t)(H * 32) * 4096 + kt * 64;
        gload_lds16(src, dst);
        gload_lds16(src + (size_t)128 * 4096, dst + 8192);
    };
    auto rdA = [&](int c, int H) {
        const char* base = smem + c * 65536 + H * 16384;
        #pragma unroll
        for (int i = 0; i < 4; ++i)
            #pragma unroll
            for (int ks = 0; ks < 2; ++ks) {
                const int w  = wr * 64 + i * 16 + lr;       // row within region
                const int cb = ks * 64 + lkb;
                aA[i][ks] = *(const bf16x8*)(base + w * 128 + (cb ^ keyx));
            }
    };
    auto rdB = [&](bf16x8 (&dst)[2][2], int c, int H) {
        const char* base = smem + c * 65536 + 32768 + H * 16384;
        #pragma unroll
        for (int j = 0; j < 2; ++j)
            #pragma unroll
            for (int ks = 0; ks < 2; ++ks) {
                const int w  = wc * 32 + j * 16 + lr;       // row within region
                const int cb = ks * 64 + lkb;
                dst[j][ks] = *(const bf16x8*)(base + w * 128 + (cb ^ keyx));
            }
    };
    auto quad = [&](f32x4 (&a)[4][2], bf16x8 (&av)[4][2], bf16x8 (&bv)[2][2]) {
        __builtin_amdgcn_s_setprio(1);
        #pragma unroll
        for (int ks = 0; ks < 2; ++ks)
            #pragma unroll
            for (int i = 0; i < 4; ++i)
                #pragma unroll
                for (int j = 0; j < 2; ++j)
                    a[i][j] = __builtin_amdgcn_mfma_f32_16x16x32_bf16(
                        av[i][ks], bv[j][ks], a[i][j], 0, 0, 0);
        __builtin_amdgcn_s_setprio(0);
    };
    #define BAR() __builtin_amdgcn_s_barrier()
    #define LG0() asm volatile("s_waitcnt lgkmcnt(0)" ::: "memory")

    // prologue: tile 0 complete (8 loads) + tile 1 {A0,B0,A1} (6 loads);
    // vmcnt(6) drains tile 0, leaves tile 1's 3 halves in flight (invariant).
    stageA(0, 0, 0); stageB(0, 0, 0); stageB(0, 1, 0); stageA(0, 1, 0);
    stageA(1, 0, 1); stageB(1, 0, 1); stageA(1, 1, 1);
    asm volatile("s_waitcnt vmcnt(6)" ::: "memory");
    BAR();

    #pragma unroll 2
    for (int t = 0; t < 62; ++t) {
        const int c = t & 1, o = c ^ 1;
        // P1
        rdA(c, 0);
        rdB(bB0, c, 0);
        stageB(o, 1, t + 1);            // B1(t+1) -> buf o
        BAR(); LG0();
        quad(acc[0][0], aA, bB0);
        BAR();
        // P2
        rdB(bB1, c, 1);
        stageA(c, 0, t + 2);            // A0(t+2) -> buf c
        BAR(); LG0();
        quad(acc[0][1], aA, bB1);
        BAR();
        // P3
        rdA(c, 1);
        stageB(c, 0, t + 2);            // B0(t+2) -> buf c
        BAR(); LG0();
        quad(acc[1][1], aA, bB1);
        BAR();
        // P4
        stageA(c, 1, t + 2);            // A1(t+2) -> buf c
        asm volatile("s_waitcnt vmcnt(6)" ::: "memory");
        BAR();
        quad(acc[1][0], aA, bB0);
        BAR();
    }

    // t = 62 (c=0, o=1): only B1(63) remains to stage; drain fully at P4
    {
        rdA(0, 0);
        rdB(bB0, 0, 0);
        stageB(1, 1, 63);
        BAR(); LG0();
        quad(acc[0][0], aA, bB0);
        BAR();
        rdB(bB1, 0, 1);
        BAR(); LG0();
        quad(acc[0][1], aA, bB1);
        BAR();
        rdA(0, 1);
        BAR(); LG0();
        quad(acc[1][1], aA, bB1);
        BAR();
        asm volatile("s_waitcnt vmcnt(0)" ::: "memory");
        BAR();
        quad(acc[1][0], aA, bB0);
    }
    // t = 63 (buf 1): reads only; no writes pending anywhere
    {
        rdA(1, 0);
        rdB(bB0, 1, 0);
        quad(acc[0][0], aA, bB0);
        rdB(bB1, 1, 1);
        quad(acc[0][1], aA, bB1);
        rdA(1, 1);
        quad(acc[1][1], aA, bB1);
        quad(acc[1][0], aA, bB0);
    }
    #undef BAR
    #undef LG0

    // epilogue: out = tanh(acc + zs[p%4][c] + bias[c])
    // C/D layout (m89): col = lane&15, row = (lane>>4)*4 + q; p%4 == q here.
    const int lq = lane >> 4;
    #pragma unroll
    for (int qn = 0; qn < 2; ++qn)
        #pragma unroll
        for (int j = 0; j < 2; ++j) {
            const int ccol = col0 + wc * 64 + qn * 32 + j * 16 + lr;
            const float bb = bias[ccol];
            float zrow[4];
            #pragma unroll
            for (int q = 0; q < 4; ++q) zrow[q] = zs[q * 2048 + ccol] + bb;
            #pragma unroll
            for (int qm = 0; qm < 2; ++qm)
                #pragma unroll
                for (int i = 0; i < 4; ++i) {
                    const int prow = row0 + wr * 128 + qm * 64 + i * 16 + lq * 4;
                    #pragma unroll
                    for (int q = 0; q < 4; ++q)
                        out[(size_t)(prow + q) * 2048 + ccol] =
                            tanh_fast(acc[qm][qn][i][j][q] + zrow[q]);
                }
        }
}

// ---------------------------------------------------------------------------
extern "C" void kernel_launch(void* const* d_in, const int* in_sizes, int n_in,
                              void* d_out, int out_size, void* d_ws, size_t ws_size,
                              hipStream_t stream) {
    const float* e1 = (const float*)d_in[0];   // (8192, 2048)
    const float* e2 = (const float*)d_in[1];   // (8192, 2048)
    const float* W  = (const float*)d_in[2];   // (2048, 2048)
    const float* V  = (const float*)d_in[3];   // (4096, 2048)
    const float* b  = (const float*)d_in[4];   // (2048,)
    float* out = (float*)d_out;                // (8192, 2048) f32

    char* ws = (char*)d_ws;
    bf16*  Xb = (bf16*)ws;                                  // 64 MiB
    bf16*  Vt = (bf16*)(ws + (size_t)64 * 1024 * 1024);     // 16 MiB
    float* zs = (float*)(ws + (size_t)80 * 1024 * 1024);    // 32 KiB

    conv_x_zs<<<8192, 256, 0, stream>>>(e1, e2, W, Xb, zs);
    conv_vt<<<2048, 256, 0, stream>>>(V, Vt);

    hipFuncSetAttribute((const void*)gemm_ep,
                        hipFuncAttributeMaxDynamicSharedMemorySize, 131072);
    gemm_ep<<<256, 512, 131072, stream>>>(Xb, Vt, zs, b, out);
}